// Round 7
// baseline (103.081 us; speedup 1.0000x reference)
//
#include <hip/hip_runtime.h>
#include <math.h>

// Problem constants (from reference setup_inputs)
#define B 64
#define N 128            // logits H=W
#define M 136            // targets H=W
#define S2 9             // shift cols (and rows)
#define S 81
#define NPIX (N*N)       // 16384
#define MPIX (M*M)       // 18496
#define CENTER 40        // 4*9 + 4
#define MF4 34           // float4 per y row
#define YF4 4624         // float4 per y image (MPIX/4)

// Fast softplus for the shift-independent BCE term: max(x,0)+log1p(exp(-|x|)).
// This term does NOT affect the argmin (argmin_s(P - D_s) == argmax_s D_s).
__device__ __forceinline__ float softplus_f(float x) {
    float t = __expf(-fabsf(x));
    return fmaxf(x, 0.0f) + __logf(1.0f + t);
}

// VALU-pipe cross-lane add: x + (x rotated right by n within each 16-lane row).
// After ctrl 0x128,0x124,0x122,0x121 every lane holds its row-of-16 sum.
#define ROR_ADD(x, CTRL) ((x) + __int_as_float(__builtin_amdgcn_update_dpp( \
        0, __float_as_int(x), (CTRL), 0xf, 0xf, true)))

// Gather this block's 1024 output quads (disjoint across the 4 siblings).
// Q in [q*1024, (q+1)*1024): quad index within the batch (4096 total).
template <int O>
__device__ __forceinline__ void gather2(const float4* yl4, float* dstB,
                                        int q, int tid, int i2, int j2) {
    #pragma unroll
    for (int k2 = 0; k2 < 2; ++k2) {
        int Q = q * 1024 + tid + 512 * k2;        // quad index, < 4096
        int row = (Q >> 5) + i2;                  // y row <= 127+8 = 135
        int i0 = (Q & 31) + (j2 >> 2);            // aligned f4 col (<= 33)
        float4 A = yl4[row * MF4 + i0];
        float r0, r1, r2, r3;
        if (O == 0) { r0 = A.x; r1 = A.y; r2 = A.z; r3 = A.w; }
        else {
            float4 Bq = yl4[row * MF4 + i0 + 1];  // O!=0 -> j2%4!=0 -> i0+1 <= 33
            if (O == 1)      { r0 = A.y; r1 = A.z; r2 = A.w; r3 = Bq.x; }
            else if (O == 2) { r0 = A.z; r1 = A.w; r2 = Bq.x; r3 = Bq.y; }
            else             { r0 = A.w; r1 = Bq.x; r2 = Bq.y; r3 = Bq.z; }
        }
        float* d = dstB + 4 * Q;   // out+1 breaks 16B alignment: scalar stores
        d[0] = r0; d[1] = r1; d[2] = r2; d[3] = r3;
    }
}

// ---------------- Single fused kernel, no inter-block dependency -------------
// 256 blocks = 4 per batch, 512 threads (8 waves -> 2 waves/SIMD), ~85 KB LDS
// (1 block/CU). Sibling decode b = bid&63, q = bid>>6 keeps all 4 siblings of
// a batch on one XCD (round-robin bid%8) so y[b] is fetched into ONE L2.
// Every block redundantly computes the FULL 81-shift correlation D[b][s] in
// identical order -> bit-identical argmax across siblings (no cross-block
// communication; every output location has exactly one writer).
// R7 = R5 base (plain float4 staging, compiler-scheduled inner loop)
//      + hoisted x loads + wave-parallel argmax.  (R6's global_load_lds
//      staging with per-lane LDS dest likely waterfalled: +11 us — reverted.)
__global__ __launch_bounds__(512, 1) void k_all(const float* __restrict__ x,
                                                const float* __restrict__ y,
                                                float* __restrict__ out) {
    const int tid = threadIdx.x;
    const int b = blockIdx.x & 63;      // batch
    const int q = blockIdx.x >> 6;      // sibling 0..3 (same XCD for fixed b)

    __shared__ float ylds[MPIX];        // 73984 B: full y[b]
    __shared__ float part[32][84];      // per row-of-16 partials (pad 84)
    __shared__ float dsum[S];
    __shared__ float spart[8];
    __shared__ int sij;

    const float4* yl4 = (const float4*)ylds;
    const float4* yg4 = (const float4*)(y + (size_t)b * MPIX);
    const float4* xg4 = (const float4*)(x + (size_t)b * NPIX);

    const int cq = tid & 31;            // column quad (0..31)
    const int rbt = (tid >> 5) * 8;     // 8-row vertical run base (0..120)

    // ---- hoist ALL x quads for this thread (8 rows); in flight under staging
    float4 xq[8];
    #pragma unroll
    for (int r = 0; r < 8; ++r) xq[r] = xg4[(rbt + r) * 32 + cq];

    // ---- stage full y[b] into LDS (float4, coalesced, conflict-free) -------
    {
        float4* yd = (float4*)ylds;
        #pragma unroll
        for (int t = 0; t < 10; ++t) {
            int idx = tid + 512 * t;
            if (idx < YF4) yd[idx] = yg4[idx];
        }
    }
    __syncthreads();

    float acc[S];
    #pragma unroll
    for (int s = 0; s < S; ++s) acc[s] = 0.0f;
    float sp = 0.0f;

    // ---- main loop: 2 sub-runs of 4 quad-rows; 12-row y window each --------
    #pragma unroll 1
    for (int k = 0; k < 2; ++k) {
        const float4 xc0 = xq[k * 4 + 0];
        const float4 xc1 = xq[k * 4 + 1];
        const float4 xc2 = xq[k * 4 + 2];
        const float4 xc3 = xq[k * 4 + 3];

        if (q == 0) {   // block-uniform: softplus sum over this block's x
            sp += softplus_f(xc0.x) + softplus_f(xc0.y) + softplus_f(xc0.z) + softplus_f(xc0.w)
                + softplus_f(xc1.x) + softplus_f(xc1.y) + softplus_f(xc1.z) + softplus_f(xc1.w)
                + softplus_f(xc2.x) + softplus_f(xc2.y) + softplus_f(xc2.z) + softplus_f(xc2.w)
                + softplus_f(xc3.x) + softplus_f(xc3.y) + softplus_f(xc3.z) + softplus_f(xc3.w);
        }

        const int yrb = rbt + k * 4;    // first y row of this window
        #pragma unroll
        for (int rr = 0; rr < 12; ++rr) {
            const float4* yrow = yl4 + (yrb + rr) * MF4 + cq;
            float4 A = yrow[0];
            float4 Bq = yrow[1];
            float4 Cq = yrow[2];
            float ya[12];
            ya[0] = A.x;  ya[1] = A.y;  ya[2] = A.z;  ya[3] = A.w;
            ya[4] = Bq.x; ya[5] = Bq.y; ya[6] = Bq.z; ya[7] = Bq.w;
            ya[8] = Cq.x; ya[9] = Cq.y; ya[10] = Cq.z; ya[11] = Cq.w;
            #pragma unroll
            for (int v = 0; v < 4; ++v) {
                const int ii = rr - v;                 // shift row
                if (ii >= 0 && ii <= 8) {              // compile-time after unroll
                    const float4 xv = (v == 0) ? xc0 : (v == 1) ? xc1
                                    : (v == 2) ? xc2 : xc3;
                    #pragma unroll
                    for (int j = 0; j < 9; ++j) {
                        acc[ii * 9 + j] += xv.x * ya[j]     + xv.y * ya[j + 1]
                                         + xv.z * ya[j + 2] + xv.w * ya[j + 3];
                    }
                }
            }
        }
    }

    // ---- reduce: row-of-16 sums on the VALU pipe (DPP), then LDS ------------
    #pragma unroll
    for (int s = 0; s < S; ++s) {
        float v = acc[s];
        v = ROR_ADD(v, 0x128);   // +ror16:8
        v = ROR_ADD(v, 0x124);   // +ror16:4
        v = ROR_ADD(v, 0x122);   // +ror16:2
        v = ROR_ADD(v, 0x121);   // +ror16:1
        acc[s] = v;              // every lane now holds its row-of-16 sum
    }
    if ((tid & 15) == 0) {
        const int g = tid >> 4;  // 0..31
        #pragma unroll
        for (int s = 0; s < S; ++s) part[g][s] = acc[s];
    }
    if (q == 0) {
        #pragma unroll
        for (int m = 1; m < 64; m <<= 1) sp += __shfl_xor(sp, m, 64);
        if ((tid & 63) == 0) spart[tid >> 6] = sp;
    }
    __syncthreads();

    if (tid < S) {
        float s0 = 0.0f;
        #pragma unroll
        for (int g = 0; g < 32; ++g) s0 += part[g][tid];   // fixed order
        dsum[tid] = s0;
    }
    __syncthreads();

    // ---- wave-parallel argmax over 81 (first-index tiebreak, then center) ---
    if (tid < 64) {
        float bv = dsum[tid];
        int   bi = tid;
        if (tid < S - 64) {                      // fold entries 64..80 in
            float v2 = dsum[64 + tid];
            if (v2 > bv) { bv = v2; bi = 64 + tid; }   // larger idx: strict >
        }
        #pragma unroll
        for (int m = 1; m < 64; m <<= 1) {
            float ov = __shfl_xor(bv, m, 64);
            int   oi = __shfl_xor(bi, m, 64);
            if (ov > bv || (ov == bv && oi < bi)) { bv = ov; bi = oi; }
        }
        if (tid == 0) {
            if (dsum[CENTER] == bv) bi = CENTER;  // center tiebreak
            sij = bi;
            if (q == 0) {
                out[1 + B * NPIX + b]     = (float)(bi / S2);   // row_shifts
                out[1 + B * NPIX + B + b] = (float)(bi % S2);   // col_shifts
                float P = 0.0f;
                #pragma unroll
                for (int w = 0; w < 8; ++w) P += spart[w];
                // per-batch min_loss; out[0] zeroed by harness before launch
                atomicAdd(out, (P - bv) * (1.0f / (float)NPIX));
            }
        }
    }
    __syncthreads();

    // ---- gather this block's quarter of adjusted_labels from LDS ------------
    {
        const int ij = sij;
        const int i2 = ij / S2, j2 = ij - i2 * S2;
        float* dstB = out + 1 + (size_t)b * NPIX;
        const int o = j2 & 3;                     // block-uniform branch
        if (o == 0)      gather2<0>(yl4, dstB, q, tid, i2, j2);
        else if (o == 1) gather2<1>(yl4, dstB, q, tid, i2, j2);
        else if (o == 2) gather2<2>(yl4, dstB, q, tid, i2, j2);
        else             gather2<3>(yl4, dstB, q, tid, i2, j2);
    }
}

extern "C" void kernel_launch(void* const* d_in, const int* in_sizes, int n_in,
                              void* d_out, int out_size, void* d_ws, size_t ws_size,
                              hipStream_t stream) {
    const float* x = (const float*)d_in[0];   // logits (64,1,128,128)
    const float* y = (const float*)d_in[1];   // targets (64,1,136,136)
    float* out = (float*)d_out;               // [1 + 64*16384 + 64 + 64]

    k_all<<<dim3(B * 4), 512, 0, stream>>>(x, y, out);
}

// Round 9
// 93.849 us; speedup vs baseline: 1.0984x; 1.0984x over previous
//
#include <hip/hip_runtime.h>
#include <math.h>

// Problem constants (from reference setup_inputs)
#define B 64
#define N 128            // logits H=W
#define M 136            // targets H=W
#define S2 9             // shift cols (and rows)
#define S 81
#define NPIX (N*N)       // 16384
#define MPIX (M*M)       // 18496
#define CENTER 40        // 4*9 + 4
#define STRIPS 16        // row strips per batch
#define SROWS 8          // x rows per strip
#define YR 16            // y rows staged per strip (8 + 8 window)
#define YF4S 544         // float4 staged per strip (16*34)

// Fast softplus for the shift-independent BCE term: max(x,0)+log1p(exp(-|x|)).
// exp arg <= 0 so t in (0,1], 1+t in (1,2] -> native log is accurate there.
// This term does NOT affect the argmin (argmin_s(P - D_s) == argmax_s D_s).
__device__ __forceinline__ float softplus_f(float x) {
    float t = __expf(-fabsf(x));
    return fmaxf(x, 0.0f) + __logf(1.0f + t);
}

// VALU-pipe cross-lane add: x + (x rotated right by n within each 16-lane row).
// After ctrl 0x128,0x124,0x122,0x121 every lane holds its row-of-16 sum.
#define ROR_ADD(x, CTRL) ((x) + __int_as_float(__builtin_amdgcn_update_dpp( \
        0, __float_as_int(x), (CTRL), 0xf, 0xf, true)))

// ---------------- Kernel 1: strip correlation partials (no redundancy) -------
// grid = B*STRIPS = 1024 blocks (b = bid>>4, st = bid&15), 256 threads.
// Occupancy: LDS ~14 KB -> 4 blocks/CU -> 16 waves/CU (4/SIMD).
// Thread (lr = tid>>5, cq = tid&31) owns x quad (row st*8+lr, cols 4cq..4cq+3),
// accumulates all 81 shifts over its quad, then 16-lane DPP reduce + LDS.
// D2[b][st][s] written in a fixed deterministic order; P2[b][st] = softplus
// partial over the strip's x rows.
__global__ __launch_bounds__(256, 4) void k_corr(const float* __restrict__ x,
                                                 const float* __restrict__ y,
                                                 float* __restrict__ D2,
                                                 float* __restrict__ P2) {
    const int tid = threadIdx.x;
    const int b  = blockIdx.x >> 4;
    const int st = blockIdx.x & 15;

    __shared__ float ylds[YR * M];      // 8704 B: y rows [st*8, st*8+16)
    __shared__ float part[16][81];      // 5184 B
    __shared__ float spart[4];

    const int lr = tid >> 5;            // strip-local x row 0..7
    const int cq = tid & 31;            // column quad 0..31

    // x quad for this thread (read once, global/L2)
    const float4 xv = ((const float4*)(x + (size_t)b * NPIX
                                         + (st * SROWS + lr) * N))[cq];

    // stage y rows [st*8, st*8+16): 544 float4, coalesced
    {
        const float4* ysrc = (const float4*)(y + (size_t)b * MPIX + st * SROWS * M);
        float4* ydst = (float4*)ylds;
        #pragma unroll
        for (int t = 0; t < 3; ++t) {
            int idx = tid + 256 * t;
            if (idx < YF4S) ydst[idx] = ysrc[idx];
        }
    }

    // softplus partial over this thread's 4 x values (block covers strip once)
    float sp = softplus_f(xv.x) + softplus_f(xv.y)
             + softplus_f(xv.z) + softplus_f(xv.w);

    __syncthreads();

    float acc[S];
    #pragma unroll
    for (int s = 0; s < S; ++s) acc[s] = 0.0f;

    // 9 shift rows; each reads 3 LDS quads (12-float window), 36 FMA
    #pragma unroll
    for (int ii = 0; ii < 9; ++ii) {
        const float* yrow = ylds + (lr + ii) * M + cq * 4;   // rows 0..15
        float4 A  = *(const float4*)(yrow);
        float4 Bq = *(const float4*)(yrow + 4);
        float4 Cq = *(const float4*)(yrow + 8);
        float ya[12];
        ya[0] = A.x;  ya[1] = A.y;  ya[2] = A.z;  ya[3] = A.w;
        ya[4] = Bq.x; ya[5] = Bq.y; ya[6] = Bq.z; ya[7] = Bq.w;
        ya[8] = Cq.x; ya[9] = Cq.y; ya[10] = Cq.z; ya[11] = Cq.w;
        #pragma unroll
        for (int j = 0; j < 9; ++j) {
            acc[ii * 9 + j] += xv.x * ya[j]     + xv.y * ya[j + 1]
                             + xv.z * ya[j + 2] + xv.w * ya[j + 3];
        }
    }

    // 16-lane DPP reduce (VALU pipe), then cross-group via LDS
    #pragma unroll
    for (int s = 0; s < S; ++s) {
        float v = acc[s];
        v = ROR_ADD(v, 0x128);   // +ror16:8
        v = ROR_ADD(v, 0x124);   // +ror16:4
        v = ROR_ADD(v, 0x122);   // +ror16:2
        v = ROR_ADD(v, 0x121);   // +ror16:1
        acc[s] = v;
    }
    if ((tid & 15) == 0) {
        const int g = tid >> 4;  // 0..15
        #pragma unroll
        for (int s = 0; s < S; ++s) part[g][s] = acc[s];
    }
    #pragma unroll
    for (int m = 1; m < 64; m <<= 1) sp += __shfl_xor(sp, m, 64);
    if ((tid & 63) == 0) spart[tid >> 6] = sp;
    __syncthreads();

    if (tid < S) {
        float s0 = 0.0f;
        #pragma unroll
        for (int g = 0; g < 16; ++g) s0 += part[g][tid];   // fixed order
        D2[((size_t)b * STRIPS + st) * S + tid] = s0;
    }
    if (tid == 96) {
        P2[b * STRIPS + st] = (spart[0] + spart[1]) + (spart[2] + spart[3]);
    }
}

// ---------------- Kernel 2: argmax + gather + scalar outputs ----------------
// grid = B*16 = 1024 blocks (b = bid>>4, p = bid&15), 256 threads.
// Every block of a batch redundantly computes the same fixed-order strip sum
// and argmax -> bit-identical across siblings (no communication). Block p
// gathers batch quads [p*256, p*256+256) (1 per thread) straight from global
// y (L2-resident; no staging). p==0 writes shifts + atomicAdd's the loss term.
__global__ __launch_bounds__(256) void k_out(const float* __restrict__ y,
                                             const float* __restrict__ D2,
                                             const float* __restrict__ P2,
                                             float* __restrict__ out) {
    const int tid = threadIdx.x;
    const int b = blockIdx.x >> 4;
    const int p = blockIdx.x & 15;

    __shared__ float dsum[S];
    __shared__ int sij;

    if (tid < S) {
        float s0 = 0.0f;
        #pragma unroll
        for (int st = 0; st < STRIPS; ++st)          // fixed order
            s0 += D2[((size_t)b * STRIPS + st) * S + tid];
        dsum[tid] = s0;
    }
    __syncthreads();

    // wave-parallel argmax over 81 (first-index tiebreak, then center)
    if (tid < 64) {
        float bv = dsum[tid];
        int   bi = tid;
        if (tid < S - 64) {                          // fold entries 64..80
            float v2 = dsum[64 + tid];
            if (v2 > bv) { bv = v2; bi = 64 + tid; } // larger idx: strict >
        }
        #pragma unroll
        for (int m = 1; m < 64; m <<= 1) {
            float ov = __shfl_xor(bv, m, 64);
            int   oi = __shfl_xor(bi, m, 64);
            if (ov > bv || (ov == bv && oi < bi)) { bv = ov; bi = oi; }
        }
        if (tid == 0) {
            if (dsum[CENTER] == bv) bi = CENTER;     // center tiebreak
            sij = bi;
            if (p == 0) {
                out[1 + B * NPIX + b]     = (float)(bi / S2);   // row_shifts
                out[1 + B * NPIX + B + b] = (float)(bi % S2);   // col_shifts
                float P = 0.0f;
                #pragma unroll
                for (int st = 0; st < STRIPS; ++st) P += P2[b * STRIPS + st];
                // per-batch min_loss; out[0] zeroed by harness before launch
                atomicAdd(out, (P - bv) * (1.0f / (float)NPIX));
            }
        }
    }
    __syncthreads();

    // gather: 1 output quad per thread, scalar loads absorb j2 misalignment
    {
        const int ij = sij;
        const int i2 = ij / S2, j2 = ij - i2 * S2;
        const int Q = p * 256 + tid;                 // batch quad 0..4095
        const int row = (Q >> 5) + i2;               // y row <= 135
        const float* yrow = y + (size_t)b * MPIX + row * M + (Q & 31) * 4 + j2;
        float* d = out + 1 + (size_t)b * NPIX + 4 * Q;
        d[0] = yrow[0]; d[1] = yrow[1]; d[2] = yrow[2]; d[3] = yrow[3];
    }
}

extern "C" void kernel_launch(void* const* d_in, const int* in_sizes, int n_in,
                              void* d_out, int out_size, void* d_ws, size_t ws_size,
                              hipStream_t stream) {
    const float* x = (const float*)d_in[0];   // logits (64,1,128,128)
    const float* y = (const float*)d_in[1];   // targets (64,1,136,136)
    float* out = (float*)d_out;               // [1 + 64*16384 + 64 + 64]

    float* wsF = (float*)d_ws;
    float* D2  = wsF;                         // 64*16*81 floats
    float* P2  = wsF + B * STRIPS * S;        // 64*16 floats

    k_corr<<<dim3(B * STRIPS), 256, 0, stream>>>(x, y, D2, P2);
    k_out<<<dim3(B * 16), 256, 0, stream>>>(y, D2, P2, out);
}

// Round 10
// 74.545 us; speedup vs baseline: 1.3828x; 1.2589x over previous
//
#include <hip/hip_runtime.h>
#include <math.h>

// Problem constants (from reference setup_inputs)
#define B 64
#define N 128            // logits H=W
#define M 136            // targets H=W
#define S2 9             // shift cols (and rows)
#define S 81
#define NPIX (N*N)       // 16384
#define MPIX (M*M)       // 18496
#define CENTER 40        // 4*9 + 4
#define STRIPS 16        // row strips per batch
#define SROWS 8          // x rows per strip
#define YR 16            // y rows staged per strip (8 + 8 window)
#define YF4S 544         // float4 staged per strip (16*34)

// Fast softplus for the shift-independent BCE term: max(x,0)+log1p(exp(-|x|)).
// exp arg <= 0 so t in (0,1], 1+t in (1,2] -> native log is accurate there.
// This term does NOT affect the argmin (argmin_s(P - D_s) == argmax_s D_s).
__device__ __forceinline__ float softplus_f(float x) {
    float t = __expf(-fabsf(x));
    return fmaxf(x, 0.0f) + __logf(1.0f + t);
}

// VALU-pipe cross-lane add: x + (x rotated right by n within each 16-lane row).
// After ctrl 0x128,0x124,0x122,0x121 every lane holds its row-of-16 sum.
#define ROR_ADD(x, CTRL) ((x) + __int_as_float(__builtin_amdgcn_update_dpp( \
        0, __float_as_int(x), (CTRL), 0xf, 0xf, true)))

// ---------------- Kernel 1: strip correlation partials (no redundancy) -------
// grid = B*STRIPS = 1024 blocks (b = bid>>4, st = bid&15), 256 threads.
// Thread (lr = tid>>5, cq = tid&31) owns x quad (row st*8+lr, cols 4cq..4cq+3).
// KEY CHANGE vs R9: acc[81] was never accumulated across the ii-loop, so the
// 9 j-accumulators of each shift-row are reduced+flushed to LDS inside the
// ii iteration. Live VGPRs drop ~110 -> ~40: no spill at the 128 cap, full
// occupancy (4 blocks/CU, 16 waves/CU), scheduler slack restored.
// D2[b][st][s] written in a fixed deterministic order; P2[b][st] = softplus
// partial over the strip's x rows. Per-(ii,j) FP order identical to R9.
__global__ __launch_bounds__(256, 4) void k_corr(const float* __restrict__ x,
                                                 const float* __restrict__ y,
                                                 float* __restrict__ D2,
                                                 float* __restrict__ P2) {
    const int tid = threadIdx.x;
    const int b  = blockIdx.x >> 4;
    const int st = blockIdx.x & 15;

    __shared__ float ylds[YR * M];      // 8704 B: y rows [st*8, st*8+16)
    __shared__ float part[16][81];      // 5184 B
    __shared__ float spart[4];

    const int lr = tid >> 5;            // strip-local x row 0..7
    const int cq = tid & 31;            // column quad 0..31

    // x quad for this thread (read once, global/L2)
    const float4 xv = ((const float4*)(x + (size_t)b * NPIX
                                         + (st * SROWS + lr) * N))[cq];

    // stage y rows [st*8, st*8+16): 544 float4, coalesced
    {
        const float4* ysrc = (const float4*)(y + (size_t)b * MPIX + st * SROWS * M);
        float4* ydst = (float4*)ylds;
        #pragma unroll
        for (int t = 0; t < 3; ++t) {
            int idx = tid + 256 * t;
            if (idx < YF4S) ydst[idx] = ysrc[idx];
        }
    }

    // softplus partial over this thread's 4 x values (block covers strip once)
    float sp = softplus_f(xv.x) + softplus_f(xv.y)
             + softplus_f(xv.z) + softplus_f(xv.w);

    __syncthreads();

    const int g = tid >> 4;             // 16-lane group id 0..15
    const bool lead = (tid & 15) == 0;

    // 9 shift rows; per row: 3 ds_read_b128, 36 FMA, 36 DPP-adds, 9 LDS flush
    #pragma unroll
    for (int ii = 0; ii < 9; ++ii) {
        const float* yrow = ylds + (lr + ii) * M + cq * 4;   // rows 0..15
        float4 A  = *(const float4*)(yrow);
        float4 Bq = *(const float4*)(yrow + 4);
        float4 Cq = *(const float4*)(yrow + 8);
        float ya[12];
        ya[0] = A.x;  ya[1] = A.y;  ya[2] = A.z;  ya[3] = A.w;
        ya[4] = Bq.x; ya[5] = Bq.y; ya[6] = Bq.z; ya[7] = Bq.w;
        ya[8] = Cq.x; ya[9] = Cq.y; ya[10] = Cq.z; ya[11] = Cq.w;
        #pragma unroll
        for (int j = 0; j < 9; ++j) {
            float v = xv.x * ya[j]     + xv.y * ya[j + 1]
                    + xv.z * ya[j + 2] + xv.w * ya[j + 3];
            v = ROR_ADD(v, 0x128);   // +ror16:8
            v = ROR_ADD(v, 0x124);   // +ror16:4
            v = ROR_ADD(v, 0x122);   // +ror16:2
            v = ROR_ADD(v, 0x121);   // +ror16:1  -> 16-lane sum in every lane
            if (lead) part[g][ii * 9 + j] = v;
        }
    }

    #pragma unroll
    for (int m = 1; m < 64; m <<= 1) sp += __shfl_xor(sp, m, 64);
    if ((tid & 63) == 0) spart[tid >> 6] = sp;
    __syncthreads();

    if (tid < S) {
        float s0 = 0.0f;
        #pragma unroll
        for (int gg = 0; gg < 16; ++gg) s0 += part[gg][tid];   // fixed order
        D2[((size_t)b * STRIPS + st) * S + tid] = s0;
    }
    if (tid == 96) {
        P2[b * STRIPS + st] = (spart[0] + spart[1]) + (spart[2] + spart[3]);
    }
}

// ---------------- Kernel 2: argmax + gather + scalar outputs ----------------
// grid = B*16 = 1024 blocks (b = bid>>4, p = bid&15), 256 threads.
// Every block of a batch redundantly computes the same fixed-order strip sum
// and argmax -> bit-identical across siblings (no communication). Block p
// gathers batch quads [p*256, p*256+256) (1 per thread) straight from global
// y (L2-resident; no staging). p==0 writes shifts + atomicAdd's the loss term.
__global__ __launch_bounds__(256) void k_out(const float* __restrict__ y,
                                             const float* __restrict__ D2,
                                             const float* __restrict__ P2,
                                             float* __restrict__ out) {
    const int tid = threadIdx.x;
    const int b = blockIdx.x >> 4;
    const int p = blockIdx.x & 15;

    __shared__ float dsum[S];
    __shared__ int sij;

    if (tid < S) {
        float s0 = 0.0f;
        #pragma unroll
        for (int st = 0; st < STRIPS; ++st)          // fixed order
            s0 += D2[((size_t)b * STRIPS + st) * S + tid];
        dsum[tid] = s0;
    }
    __syncthreads();

    // wave-parallel argmax over 81 (first-index tiebreak, then center)
    if (tid < 64) {
        float bv = dsum[tid];
        int   bi = tid;
        if (tid < S - 64) {                          // fold entries 64..80
            float v2 = dsum[64 + tid];
            if (v2 > bv) { bv = v2; bi = 64 + tid; } // larger idx: strict >
        }
        #pragma unroll
        for (int m = 1; m < 64; m <<= 1) {
            float ov = __shfl_xor(bv, m, 64);
            int   oi = __shfl_xor(bi, m, 64);
            if (ov > bv || (ov == bv && oi < bi)) { bv = ov; bi = oi; }
        }
        if (tid == 0) {
            if (dsum[CENTER] == bv) bi = CENTER;     // center tiebreak
            sij = bi;
            if (p == 0) {
                out[1 + B * NPIX + b]     = (float)(bi / S2);   // row_shifts
                out[1 + B * NPIX + B + b] = (float)(bi % S2);   // col_shifts
                float P = 0.0f;
                #pragma unroll
                for (int st = 0; st < STRIPS; ++st) P += P2[b * STRIPS + st];
                // per-batch min_loss; out[0] zeroed by harness before launch
                atomicAdd(out, (P - bv) * (1.0f / (float)NPIX));
            }
        }
    }
    __syncthreads();

    // gather: 1 output quad per thread, scalar loads absorb j2 misalignment
    {
        const int ij = sij;
        const int i2 = ij / S2, j2 = ij - i2 * S2;
        const int Q = p * 256 + tid;                 // batch quad 0..4095
        const int row = (Q >> 5) + i2;               // y row <= 135
        const float* yrow = y + (size_t)b * MPIX + row * M + (Q & 31) * 4 + j2;
        float* d = out + 1 + (size_t)b * NPIX + 4 * Q;
        d[0] = yrow[0]; d[1] = yrow[1]; d[2] = yrow[2]; d[3] = yrow[3];
    }
}

extern "C" void kernel_launch(void* const* d_in, const int* in_sizes, int n_in,
                              void* d_out, int out_size, void* d_ws, size_t ws_size,
                              hipStream_t stream) {
    const float* x = (const float*)d_in[0];   // logits (64,1,128,128)
    const float* y = (const float*)d_in[1];   // targets (64,1,136,136)
    float* out = (float*)d_out;               // [1 + 64*16384 + 64 + 64]

    float* wsF = (float*)d_ws;
    float* D2  = wsF;                         // 64*16*81 floats
    float* P2  = wsF + B * STRIPS * S;        // 64*16 floats

    k_corr<<<dim3(B * STRIPS), 256, 0, stream>>>(x, y, D2, P2);
    k_out<<<dim3(B * 16), 256, 0, stream>>>(y, D2, P2, out);
}